// Round 8
// baseline (445.834 us; speedup 1.0000x reference)
//
#include <hip/hip_runtime.h>
#include <hip/hip_bf16.h>

// Problem constants (MultiTaskFEGIN): N=100000, E=1200000, F=32, H=64, L=3,
// G=256, C=200000, NC=10, D=L*H=192.

#define GG 256
#define NCC 10
#define DD 192
#define BSH 9          // bucket shift: 512 nodes/bucket (NB <= 256 for N <= 131072)

typedef short bf16x8 __attribute__((ext_vector_type(8)));
typedef float f32x4  __attribute__((ext_vector_type(4)));

__device__ inline unsigned short f2bf_u(float x) {
    __hip_bfloat16 h = __float2bfloat16(x);
    return *reinterpret_cast<unsigned short*>(&h);
}
__device__ inline float bf2f(unsigned short u) {
    return __uint_as_float(((unsigned int)u) << 16);
}

// ---------------------------------------------------------------------------
// Binned CSR build (R6, unchanged): contiguous per-bucket scatter regions.
// ---------------------------------------------------------------------------
__global__ void bin_hist(const int* __restrict__ dst, int* __restrict__ bcnt, int E_) {
    __shared__ int h[256];
    h[threadIdx.x] = 0;
    __syncthreads();
    for (int e = blockIdx.x * 256 + threadIdx.x; e < E_; e += gridDim.x * 256)
        atomicAdd(&h[dst[e] >> BSH], 1);
    __syncthreads();
    if (h[threadIdx.x]) atomicAdd(&bcnt[threadIdx.x], h[threadIdx.x]);
}

__global__ void bin_scan(const int* __restrict__ bcnt, int* __restrict__ bbase,
                         int* __restrict__ bpos, int NB, int E_) {
    __shared__ int s[256];
    const int t = threadIdx.x;
    int v = (t < NB) ? bcnt[t] : 0;
    s[t] = v;
    __syncthreads();
    for (int off = 1; off < 256; off <<= 1) {
        int x = (t >= off) ? s[t - off] : 0;
        __syncthreads();
        s[t] += x;
        __syncthreads();
    }
    if (t < NB) { bbase[t] = s[t] - v; bpos[t] = s[t] - v; }
    if (t == 0) bbase[NB] = E_;
}

__global__ __launch_bounds__(256) void bin_scatter(
    const int* __restrict__ src, const int* __restrict__ dst,
    int* __restrict__ bpos, int2* __restrict__ ebuf, int E_) {
    __shared__ int h[256];
    __shared__ int base[256];
    const int t = threadIdx.x;
    const int e0 = blockIdx.x * 2048;
    h[t] = 0;
    __syncthreads();
    int myb[8], mys[8], myd[8], myr[8];
    #pragma unroll
    for (int u = 0; u < 8; ++u) {
        int e = e0 + t + u * 256;
        if (e < E_) {
            int d = dst[e];
            myb[u] = d >> BSH;
            myd[u] = d;
            mys[u] = src[e];
            myr[u] = atomicAdd(&h[myb[u]], 1);
        } else myb[u] = -1;
    }
    __syncthreads();
    if (h[t]) base[t] = atomicAdd(&bpos[t], h[t]);
    __syncthreads();
    #pragma unroll
    for (int u = 0; u < 8; ++u)
        if (myb[u] >= 0)
            ebuf[base[myb[u]] + myr[u]] = make_int2(mys[u], myd[u]);
}

__global__ __launch_bounds__(256) void csr_bucket(
    const int2* __restrict__ ebuf, const int* __restrict__ bbase,
    int* __restrict__ rowptr, int* __restrict__ nbr, int N_, int NB) {
    __shared__ int lh[512];
    __shared__ int lx[512];
    __shared__ int ps[256];
    const int b = blockIdx.x;
    const int t = threadIdx.x;
    const int ebase = bbase[b], eend = bbase[b + 1];
    const int ecnt = eend - ebase;
    const int n0 = b << BSH;

    for (int i = t; i < 512; i += 256) lh[i] = 0;
    __syncthreads();
    for (int i = t; i < ecnt; i += 256)
        atomicAdd(&lh[ebuf[ebase + i].y - n0], 1);
    __syncthreads();

    int pv = lh[2 * t] + lh[2 * t + 1];
    ps[t] = pv;
    __syncthreads();
    for (int off = 1; off < 256; off <<= 1) {
        int x = (t >= off) ? ps[t - off] : 0;
        __syncthreads();
        ps[t] += x;
        __syncthreads();
    }
    const int excl = ps[t] - pv;
    lx[2 * t] = excl;
    lx[2 * t + 1] = excl + lh[2 * t];
    __syncthreads();

    for (int i = t; i < 512; i += 256) {
        int n = n0 + i;
        if (n < N_) rowptr[n] = ebase + lx[i];
    }
    if (b == NB - 1 && t == 0) rowptr[N_] = eend;

    for (int i = t; i < 512; i += 256) lh[i] = lx[i];
    __syncthreads();
    for (int i = t; i < ecnt; i += 256) {
        int2 p = ebuf[ebase + i];
        int r = atomicAdd(&lh[p.y - n0], 1);
        nbr[ebase + r] = p.x;
    }
}

// ---------------------------------------------------------------------------
// prep_enc: pack the 6 encoder weight matrices into MFMA B-fragment bf16.
// ---------------------------------------------------------------------------
__global__ void prep_enc(const float* __restrict__ c1W1, const float* __restrict__ c1W2,
                         const float* __restrict__ csW1, const float* __restrict__ csW2,
                         unsigned short* __restrict__ enc) {
    int idx = blockIdx.x * 256 + threadIdx.x;
    if (idx >= 22528) return;
    const float* W; int rel;
    if (idx < 2048)       { W = c1W1;        rel = idx; }
    else if (idx < 6144)  { W = c1W2;        rel = idx - 2048; }
    else if (idx < 10240) { W = csW1;        rel = idx - 6144; }
    else if (idx < 14336) { W = csW2;        rel = idx - 10240; }
    else if (idx < 18432) { W = csW1 + 4096; rel = idx - 14336; }
    else                  { W = csW2 + 4096; rel = idx - 18432; }
    int frag = rel >> 9;
    int lane = (rel >> 3) & 63;
    int j = rel & 7;
    int ks = frag >> 2, nt = frag & 3;
    int k = ks * 32 + ((lane >> 4) << 3) + j;
    int n = nt * 16 + (lane & 15);
    enc[idx] = f2bf_u(W[k * 64 + n]);
}

// ---------------------------------------------------------------------------
// gcnt: per-graph node counts (int histogram).
// ---------------------------------------------------------------------------
__global__ void gcnt_kernel(const int* __restrict__ batch, int* __restrict__ gcnt_i, int N_) {
    int i = blockIdx.x * 256 + threadIdx.x;
    if (i < N_) atomicAdd(&gcnt_i[batch[i]], 1);
}

// ---------------------------------------------------------------------------
// Fused GIN layer: combined-span chunked gather (deep ILP) -> bf16 swizzled
// LDS -> MFMA 2-layer MLP -> BN -> bf16 hb slice + fused per-slice mean-pool
// accumulation (batch sorted: per-block run-length, atomics to L2-resident
// gsum). 32 nodes/block, 512 thr. LDS ~12KB. nbr[] padded >=64 ints past E.
// ---------------------------------------------------------------------------
#define SWZ(row, byte) ((byte) ^ (((row) & 7) << 4))

template<int K>
__global__ __launch_bounds__(512) void gin_fused(
    const float* __restrict__ x32,                 // K=32: fp32 input [N][32]
    const __hip_bfloat16* __restrict__ hin_b,      // K=64: bf16 slice, stride DD
    const int* __restrict__ rowptr, const int* __restrict__ nbr,
    const unsigned short* __restrict__ W1p, const float* __restrict__ b1,
    const unsigned short* __restrict__ W2p, const float* __restrict__ b2,
    const float* __restrict__ gamma, const float* __restrict__ beta,
    const float* __restrict__ mean, const float* __restrict__ var,
    const float* __restrict__ eps_p,
    __hip_bfloat16* __restrict__ out_b,            // slice ptr, stride DD
    const int* __restrict__ batch, float* __restrict__ gsum, int soff,
    int N_) {
    __shared__ char s_agg[32 * 128];   // bf16 [32 nodes][64 k], XOR-swizzled
    __shared__ char s_h1[32 * 128];
    __shared__ char s_out[32 * 128];
    __shared__ int sb[32];

    const int t = threadIdx.x;
    const int lane = t & 63;
    const int w = t >> 6;
    const int node0 = blockIdx.x * 32;
    const int nb = w * 4;

    if (t < 32) sb[t] = (node0 + t < N_) ? batch[node0 + t] : -1;

    const float eps1 = 1.0f + eps_p[0];

    // ---- combined-span gather for this wave's 4 consecutive nodes ----
    const int n0w = node0 + nb;
    const int rp0 = __builtin_amdgcn_readfirstlane(rowptr[min(n0w + 0, N_)]);
    const int rp1 = __builtin_amdgcn_readfirstlane(rowptr[min(n0w + 1, N_)]);
    const int rp2 = __builtin_amdgcn_readfirstlane(rowptr[min(n0w + 2, N_)]);
    const int rp3 = __builtin_amdgcn_readfirstlane(rowptr[min(n0w + 3, N_)]);
    const int rp4 = __builtin_amdgcn_readfirstlane(rowptr[min(n0w + 4, N_)]);
    const int cnt = rp4 - rp0;
    const int e1 = rp1 - rp0, e2 = rp2 - rp0, e3 = rp3 - rp0;
    const int* nbp = nbr + rp0;

    float a0 = 0.f, a1 = 0.f, a2 = 0.f, a3 = 0.f;

    if (K == 64) {
        const __hip_bfloat16* hbp = hin_b + lane;
        int idxb[16];
        #pragma unroll
        for (int u = 0; u < 16; ++u) idxb[u] = nbp[u];
        for (int k = 0; k < cnt; k += 16) {
            int nxt[16];
            #pragma unroll
            for (int u = 0; u < 16; ++u) nxt[u] = nbp[k + 16 + u];
            #pragma unroll
            for (int u = 0; u < 16; ++u) {
                float v = __bfloat162float(hbp[(size_t)idxb[u] * DD]);
                int j = k + u;
                a0 += (j < e1)             ? v : 0.f;
                a1 += (j >= e1 && j < e2)  ? v : 0.f;
                a2 += (j >= e2 && j < e3)  ? v : 0.f;
                a3 += (j >= e3 && j < cnt) ? v : 0.f;
            }
            #pragma unroll
            for (int u = 0; u < 16; ++u) idxb[u] = nxt[u];
        }
        if (n0w + 0 < N_) a0 += eps1 * __bfloat162float(hbp[(size_t)(n0w + 0) * DD]);
        if (n0w + 1 < N_) a1 += eps1 * __bfloat162float(hbp[(size_t)(n0w + 1) * DD]);
        if (n0w + 2 < N_) a2 += eps1 * __bfloat162float(hbp[(size_t)(n0w + 2) * DD]);
        if (n0w + 3 < N_) a3 += eps1 * __bfloat162float(hbp[(size_t)(n0w + 3) * DD]);
        *(unsigned short*)(s_agg + SWZ(nb + 0, (nb + 0) * 128 + lane * 2)) = f2bf_u(a0);
        *(unsigned short*)(s_agg + SWZ(nb + 1, (nb + 1) * 128 + lane * 2)) = f2bf_u(a1);
        *(unsigned short*)(s_agg + SWZ(nb + 2, (nb + 2) * 128 + lane * 2)) = f2bf_u(a2);
        *(unsigned short*)(s_agg + SWZ(nb + 3, (nb + 3) * 128 + lane * 2)) = f2bf_u(a3);
    } else {
        // K == 32: fp32 rows; lanes 0-31 = even edges, 32-63 = odd edges
        const int d = lane & 31, rs = lane >> 5;
        const float* xp = x32 + d;
        int idxb[8];
        #pragma unroll
        for (int u = 0; u < 8; ++u) idxb[u] = nbp[2 * u + rs];
        for (int k = 0; k < cnt; k += 16) {
            int nxt[8];
            #pragma unroll
            for (int u = 0; u < 8; ++u) nxt[u] = nbp[k + 16 + 2 * u + rs];
            #pragma unroll
            for (int u = 0; u < 8; ++u) {
                float v = xp[(size_t)idxb[u] * 32];
                int j = k + 2 * u + rs;
                a0 += (j < e1)             ? v : 0.f;
                a1 += (j >= e1 && j < e2)  ? v : 0.f;
                a2 += (j >= e2 && j < e3)  ? v : 0.f;
                a3 += (j >= e3 && j < cnt) ? v : 0.f;
            }
            #pragma unroll
            for (int u = 0; u < 8; ++u) idxb[u] = nxt[u];
        }
        a0 += __shfl_xor(a0, 32);
        a1 += __shfl_xor(a1, 32);
        a2 += __shfl_xor(a2, 32);
        a3 += __shfl_xor(a3, 32);
        if (rs == 0) {
            if (n0w + 0 < N_) a0 += eps1 * xp[(size_t)(n0w + 0) * 32];
            if (n0w + 1 < N_) a1 += eps1 * xp[(size_t)(n0w + 1) * 32];
            if (n0w + 2 < N_) a2 += eps1 * xp[(size_t)(n0w + 2) * 32];
            if (n0w + 3 < N_) a3 += eps1 * xp[(size_t)(n0w + 3) * 32];
            *(unsigned short*)(s_agg + SWZ(nb + 0, (nb + 0) * 128 + d * 2)) = f2bf_u(a0);
            *(unsigned short*)(s_agg + SWZ(nb + 1, (nb + 1) * 128 + d * 2)) = f2bf_u(a1);
            *(unsigned short*)(s_agg + SWZ(nb + 2, (nb + 2) * 128 + d * 2)) = f2bf_u(a2);
            *(unsigned short*)(s_agg + SWZ(nb + 3, (nb + 3) * 128 + d * 2)) = f2bf_u(a3);
        }
    }
    __syncthreads();

    // ---- GEMM1: [32 x K] @ [K x 64] via MFMA; wave w -> C tile (mt, nt) ----
    const int mt = w >> 2, nt = w & 3;
    const int arow = mt * 16 + (lane & 15);
    const int col = nt * 16 + (lane & 15);
    f32x4 c1v = (f32x4){0.f, 0.f, 0.f, 0.f};
    #pragma unroll
    for (int ks = 0; ks < K / 32; ++ks) {
        bf16x8 a = *(const bf16x8*)(s_agg + SWZ(arow, arow * 128 + ks * 64 + ((lane >> 4) << 4)));
        bf16x8 b = *(const bf16x8*)(W1p + (((ks << 2) + nt) << 9) + (lane << 3));
        c1v = __builtin_amdgcn_mfma_f32_16x16x32_bf16(a, b, c1v, 0, 0, 0);
    }
    {
        const float bb1 = b1[col];
        #pragma unroll
        for (int reg = 0; reg < 4; ++reg) {
            int row = mt * 16 + ((lane >> 4) << 2) + reg;
            float v = fmaxf(c1v[reg] + bb1, 0.f);
            *(unsigned short*)(s_h1 + SWZ(row, row * 128 + col * 2)) = f2bf_u(v);
        }
    }
    __syncthreads();

    // ---- GEMM2: [32 x 64] @ [64 x 64] + BN epilogue ----
    f32x4 c2v = (f32x4){0.f, 0.f, 0.f, 0.f};
    #pragma unroll
    for (int ks = 0; ks < 2; ++ks) {
        bf16x8 a = *(const bf16x8*)(s_h1 + SWZ(arow, arow * 128 + ks * 64 + ((lane >> 4) << 4)));
        bf16x8 b = *(const bf16x8*)(W2p + (((ks << 2) + nt) << 9) + (lane << 3));
        c2v = __builtin_amdgcn_mfma_f32_16x16x32_bf16(a, b, c2v, 0, 0, 0);
    }
    {
        const float bb2 = b2[col];
        const float ga = gamma[col], bet = beta[col], mu = mean[col];
        const float iv = rsqrtf(var[col] + 1e-5f);
        #pragma unroll
        for (int reg = 0; reg < 4; ++reg) {
            int row = mt * 16 + ((lane >> 4) << 2) + reg;
            float v = fmaxf(c2v[reg] + bb2, 0.f);
            v = ga * (v - mu) * iv + bet;
            *(unsigned short*)(s_out + SWZ(row, row * 128 + col * 2)) = f2bf_u(v);
        }
    }
    __syncthreads();

    // ---- coalesced copy out: 32 rows x 128B, 16 threads/row x 8B ----
    {
        int r = t >> 4, c8 = t & 15;
        int node = node0 + r;
        if (node < N_) {
            ushort4 v = *(const ushort4*)(s_out + SWZ(r, r * 128 + c8 * 8));
            *(ushort4*)((unsigned short*)out_b + (size_t)node * DD + c8 * 4) = v;
        }
    }

    // ---- fused mean-pool accumulation for this slice (batch sorted) ----
    if (t < 256) {
        const int d = t & 63;
        const int rg = t >> 6;                  // row group 0..3 (8 rows each)
        float acc = 0.f;
        int curg = sb[rg * 8];
        #pragma unroll
        for (int r = rg * 8; r < rg * 8 + 8; ++r) {
            int g = sb[r];
            if (g != curg) {
                if (curg >= 0) atomicAdd(&gsum[curg * DD + soff + d], acc);
                acc = 0.f; curg = g;
            }
            if (g >= 0)
                acc += bf2f(*(const unsigned short*)(s_out + SWZ(r, r * 128 + d * 2)));
        }
        if (curg >= 0) atomicAdd(&gsum[curg * DD + soff + d], acc);
    }
}

// ---------------------------------------------------------------------------
// Classification head: one block per graph (fp32 throughout).
// ---------------------------------------------------------------------------
__global__ void head_kernel(const float* __restrict__ gsum, const int* __restrict__ gcnt_i,
                            const float* __restrict__ W1, const float* __restrict__ b1,
                            const float* __restrict__ W2, const float* __restrict__ b2,
                            const float* __restrict__ W3, const float* __restrict__ b3,
                            const float* __restrict__ W4, const float* __restrict__ b4,
                            float* __restrict__ class_out, int* __restrict__ comp_idx) {
    const int g = blockIdx.x;
    const int t = threadIdx.x;
    __shared__ float ge[DD], h1[128], h2[64], h3[64], logits[NCC];

    const float c = fmaxf((float)gcnt_i[g], 1.0f);
    if (t < DD) ge[t] = gsum[g * DD + t] / c;
    __syncthreads();

    if (t < 128) {
        float a = b1[t];
        #pragma unroll 4
        for (int k = 0; k < DD; ++k) a += ge[k] * W1[k * 128 + t];
        h1[t] = fmaxf(a, 0.0f);
    }
    __syncthreads();
    if (t < 64) {
        float a = b2[t];
        #pragma unroll 4
        for (int k = 0; k < 128; ++k) a += h1[k] * W2[k * 64 + t];
        h2[t] = fmaxf(a, 0.0f);
    }
    __syncthreads();
    if (t < 64) {
        float a = b3[t];
        #pragma unroll 4
        for (int k = 0; k < 64; ++k) a += h2[k] * W3[k * 64 + t];
        h3[t] = fmaxf(a, 0.0f);
    }
    __syncthreads();
    if (t < NCC) {
        float a = b4[t];
        #pragma unroll
        for (int k = 0; k < 64; ++k) a += h3[k] * W4[k * NCC + t];
        logits[t] = a;
    }
    __syncthreads();
    if (t == 0) {
        float mx = logits[0]; int am = 0;
        for (int j = 1; j < NCC; ++j) if (logits[j] > mx) { mx = logits[j]; am = j; }
        float se = 0.0f;
        for (int j = 0; j < NCC; ++j) se += expf(logits[j] - mx);
        float lse = logf(se);
        for (int j = 0; j < NCC; ++j) class_out[g * NCC + j] = logits[j] - mx - lse;
        comp_idx[g] = am;
    }
}

// ---------------------------------------------------------------------------
// prep_edge: pack ep_W1 (rows 192..383) and ep_W2 into MFMA B-fragment order;
// pc[10][128] = comp_emb @ W1a + b1.
// ---------------------------------------------------------------------------
__global__ void prep_edge(const float* __restrict__ W1, const float* __restrict__ b1,
                          const float* __restrict__ W2, const float* __restrict__ comp_emb,
                          unsigned short* __restrict__ W1b_p, unsigned short* __restrict__ W2_p,
                          float* __restrict__ pc) {
    int idx = blockIdx.x * 256 + threadIdx.x;
    const int S1 = 6 * 8 * 512;
    const int S2 = 4 * 4 * 512;
    if (idx < S1) {
        int frag = idx >> 9;
        int lane = (idx >> 3) & 63;
        int j = idx & 7;
        int kstep = frag >> 3, nt = frag & 7;
        int k = kstep * 32 + ((lane >> 4) << 3) + j;
        int n = nt * 16 + (lane & 15);
        W1b_p[idx] = f2bf_u(W1[(192 + k) * 128 + n]);
    } else if (idx < S1 + S2) {
        int i2 = idx - S1;
        int frag = i2 >> 9;
        int lane = (i2 >> 3) & 63;
        int j = i2 & 7;
        int kstep = frag >> 2, nt = frag & 3;
        int k = kstep * 32 + ((lane >> 4) << 3) + j;
        int n = nt * 16 + (lane & 15);
        W2_p[i2] = f2bf_u(W2[k * 64 + n]);
    } else if (idx < S1 + S2 + NCC * 128) {
        int i3 = idx - (S1 + S2);
        int ci = i3 >> 7, col = i3 & 127;
        float a = b1[col];
        for (int k = 0; k < DD; ++k) a += comp_emb[ci * DD + k] * W1[k * 128 + col];
        pc[i3] = a;
    }
}

// ---------------------------------------------------------------------------
// edge_mfma: 64 candidates per 256-thread block (4 waves). de rows gathered
// directly from bf16 hb (384B/row).
// ---------------------------------------------------------------------------
__global__ __launch_bounds__(256) void edge_mfma(
    const int* __restrict__ cand, const int* __restrict__ batch,
    const int* __restrict__ comp_idx, const short* __restrict__ hb,
    const unsigned short* __restrict__ W1b_p, const unsigned short* __restrict__ W2_p,
    const float* __restrict__ pc, const float* __restrict__ W3,
    const float* __restrict__ b3, float* __restrict__ scores, int C_) {
    __shared__ char s_de[64 * 384];
    __shared__ char s_h1[64 * 256];
    __shared__ int s_node[64];
    __shared__ int s_ci[64];
    __shared__ float s_pc[NCC * 128];
    __shared__ float s_w3[64];

    const int t = threadIdx.x;
    const int lane = t & 63;
    const int w = t >> 6;
    const int c0 = blockIdx.x * 64;

    if (t < 64) {
        int c = c0 + t;
        int node = (c < C_) ? cand[c] : cand[0];
        s_node[t] = node;
        s_ci[t] = comp_idx[batch[node]];
        s_w3[t] = W3[t];
    }
    for (int i = t; i < NCC * 128; i += 256) s_pc[i] = pc[i];
    __syncthreads();

    for (int i = t; i < 64 * 24; i += 256) {
        int r = i / 24, c8 = i - r * 24;
        bf16x8 v = *(const bf16x8*)(hb + (size_t)s_node[r] * DD + c8 * 8);
        int off = r * 384 + c8 * 16;
        *(bf16x8*)(s_de + (off ^ ((r & 7) << 4))) = v;
    }
    __syncthreads();

    f32x4 acc1[8];
    #pragma unroll
    for (int nt = 0; nt < 8; ++nt) acc1[nt] = (f32x4){0.f, 0.f, 0.f, 0.f};
    const int arow = w * 16 + (lane & 15);
    const int abase = arow * 384 + ((lane >> 4) << 4);
    #pragma unroll
    for (int ks = 0; ks < 6; ++ks) {
        bf16x8 a = *(const bf16x8*)(s_de + ((abase + ks * 64) ^ ((arow & 7) << 4)));
        #pragma unroll
        for (int nt = 0; nt < 8; ++nt) {
            bf16x8 b = *(const bf16x8*)(W1b_p + ((ks * 8 + nt) << 9) + (lane << 3));
            acc1[nt] = __builtin_amdgcn_mfma_f32_16x16x32_bf16(a, b, acc1[nt], 0, 0, 0);
        }
    }
    {
        const int rq = (lane >> 4) << 2;
        #pragma unroll
        for (int reg = 0; reg < 4; ++reg) {
            int row = w * 16 + rq + reg;
            int ci = s_ci[row];
            #pragma unroll
            for (int nt = 0; nt < 8; ++nt) {
                int col = nt * 16 + (lane & 15);
                float v = acc1[nt][reg] + s_pc[ci * 128 + col];
                v = fmaxf(v, 0.0f);
                int off = row * 256 + col * 2;
                *(unsigned short*)(s_h1 + (off ^ ((row & 7) << 4))) = f2bf_u(v);
            }
        }
    }
    __syncthreads();

    f32x4 acc2[4];
    #pragma unroll
    for (int nt = 0; nt < 4; ++nt) acc2[nt] = (f32x4){0.f, 0.f, 0.f, 0.f};
    const int a2base = arow * 256 + ((lane >> 4) << 4);
    #pragma unroll
    for (int ks = 0; ks < 4; ++ks) {
        bf16x8 a = *(const bf16x8*)(s_h1 + ((a2base + ks * 64) ^ ((arow & 7) << 4)));
        #pragma unroll
        for (int nt = 0; nt < 4; ++nt) {
            bf16x8 b = *(const bf16x8*)(W2_p + ((ks * 4 + nt) << 9) + (lane << 3));
            acc2[nt] = __builtin_amdgcn_mfma_f32_16x16x32_bf16(a, b, acc2[nt], 0, 0, 0);
        }
    }
    const float bb3 = b3[0];
    #pragma unroll
    for (int reg = 0; reg < 4; ++reg) {
        float p = 0.0f;
        #pragma unroll
        for (int nt = 0; nt < 4; ++nt)
            p += fmaxf(acc2[nt][reg], 0.0f) * s_w3[nt * 16 + (lane & 15)];
        p += __shfl_xor(p, 1);
        p += __shfl_xor(p, 2);
        p += __shfl_xor(p, 4);
        p += __shfl_xor(p, 8);
        if ((lane & 15) == 0) {
            int c = c0 + w * 16 + ((lane >> 4) << 2) + reg;
            if (c < C_) scores[c] = 1.0f / (1.0f + expf(-(p + bb3)));
        }
    }
}

// ---------------------------------------------------------------------------
extern "C" void kernel_launch(void* const* d_in, const int* in_sizes, int n_in,
                              void* d_out, int out_size, void* d_ws, size_t ws_size,
                              hipStream_t stream) {
    const float* x        = (const float*)d_in[0];
    const int*   ei       = (const int*)d_in[1];
    const int*   batch    = (const int*)d_in[2];
    const int*   cand     = (const int*)d_in[3];
    const float* c1_W1    = (const float*)d_in[4];
    const float* c1_b1    = (const float*)d_in[5];
    const float* c1_W2    = (const float*)d_in[6];
    const float* c1_b2    = (const float*)d_in[7];
    const float* c1_g     = (const float*)d_in[8];
    const float* c1_be    = (const float*)d_in[9];
    const float* c1_m     = (const float*)d_in[10];
    const float* c1_v     = (const float*)d_in[11];
    const float* c1_eps   = (const float*)d_in[12];
    const float* cs_W1    = (const float*)d_in[13];
    const float* cs_b1    = (const float*)d_in[14];
    const float* cs_W2    = (const float*)d_in[15];
    const float* cs_b2    = (const float*)d_in[16];
    const float* cs_g     = (const float*)d_in[17];
    const float* cs_be    = (const float*)d_in[18];
    const float* cs_m     = (const float*)d_in[19];
    const float* cs_v     = (const float*)d_in[20];
    const float* cs_eps   = (const float*)d_in[21];
    const float* nc_W1    = (const float*)d_in[22];
    const float* nc_b1    = (const float*)d_in[23];
    const float* nc_W2    = (const float*)d_in[24];
    const float* nc_b2    = (const float*)d_in[25];
    const float* nc_W3    = (const float*)d_in[26];
    const float* nc_b3    = (const float*)d_in[27];
    const float* nc_W4    = (const float*)d_in[28];
    const float* nc_b4    = (const float*)d_in[29];
    const float* comp_emb = (const float*)d_in[30];
    const float* ep_W1    = (const float*)d_in[31];
    const float* ep_b1    = (const float*)d_in[32];
    const float* ep_W2    = (const float*)d_in[33];
    const float* ep_b2    = (const float*)d_in[34];
    const float* ep_W3    = (const float*)d_in[35];
    const float* ep_b3    = (const float*)d_in[36];

    const int N_ = in_sizes[0] / 32;
    const int E_ = in_sizes[1] / 2;
    const int C_ = in_sizes[3];
    const int* src = ei;
    const int* dst = ei + E_;
    const int NB = (N_ + (1 << BSH) - 1) >> BSH;

    char* ws = (char*)d_ws;
    size_t off = 0;
    __hip_bfloat16* hb = (__hip_bfloat16*)(ws + off); off += (size_t)N_ * DD * 2;
    int*   rowptr   = (int*)(ws + off);   off += (size_t)(N_ + 2) * 4;
    int*   nbr      = (int*)(ws + off);   off += (size_t)(E_ + 64) * 4;
    int*   bcnt     = (int*)(ws + off);   off += 1024;
    int*   bbase    = (int*)(ws + off);   off += 1044;
    int*   bpos     = (int*)(ws + off);   off += 1024;
    float* gsum     = (float*)(ws + off); off += (size_t)GG * DD * 4;
    int*   gcnt_i   = (int*)(ws + off);   off += 1024;
    int*   comp_idx = (int*)(ws + off);   off += 1024;
    float* pc       = (float*)(ws + off); off += NCC * 128 * 4;
    unsigned short* W1b_p = (unsigned short*)(ws + off); off += 6 * 8 * 512 * 2;
    unsigned short* W2_p  = (unsigned short*)(ws + off); off += 4 * 4 * 512 * 2;
    unsigned short* enc   = (unsigned short*)(ws + off); off += 22528 * 2;
    // ebuf (E x int2 = 9.6MB) aliases hb: fully consumed by csr_bucket before
    // the first gin_fused writes hb (same stream, serial).
    int2*  ebuf     = (int2*)hb;

    float* class_out = (float*)d_out;
    float* scores    = class_out + GG * NCC;

    // ---- weight prep (independent of graph pipeline) ----
    prep_edge<<<(6 * 8 * 512 + 4 * 4 * 512 + NCC * 128 + 255) / 256, 256, 0, stream>>>(
        ep_W1, ep_b1, ep_W2, comp_emb, W1b_p, W2_p, pc);
    prep_enc<<<(22528 + 255) / 256, 256, 0, stream>>>(c1_W1, c1_W2, cs_W1, cs_W2, enc);

    // ---- binned CSR build ----
    hipMemsetAsync(bcnt, 0, 1024, stream);
    hipMemsetAsync(nbr + E_, 0, 64 * 4, stream);
    bin_hist<<<1024, 256, 0, stream>>>(dst, bcnt, E_);
    bin_scan<<<1, 256, 0, stream>>>(bcnt, bbase, bpos, NB, E_);
    bin_scatter<<<(E_ + 2047) / 2048, 256, 0, stream>>>(src, dst, bpos, ebuf, E_);
    csr_bucket<<<NB, 256, 0, stream>>>(ebuf, bbase, rowptr, nbr, N_, NB);

    // ---- pool accumulators (zero before fused-pool layers) ----
    hipMemsetAsync(gsum, 0, (size_t)GG * DD * 4 + 1024, stream);  // gsum + gcnt_i
    gcnt_kernel<<<(N_ + 255) / 256, 256, 0, stream>>>(batch, gcnt_i, N_);

    // ---- GIN layers (fused gather + MFMA MLP + fused pool) ----
    const int gblk = (N_ + 31) / 32;
    gin_fused<32><<<gblk, 512, 0, stream>>>(
        x, nullptr, rowptr, nbr,
        enc + 0, c1_b1, enc + 2048, c1_b2,
        c1_g, c1_be, c1_m, c1_v, c1_eps, hb + 0, batch, gsum, 0, N_);
    gin_fused<64><<<gblk, 512, 0, stream>>>(
        nullptr, hb + 0, rowptr, nbr,
        enc + 6144, cs_b1 + 0, enc + 10240, cs_b2 + 0,
        cs_g + 0, cs_be + 0, cs_m + 0, cs_v + 0, cs_eps + 0, hb + 64, batch, gsum, 64, N_);
    gin_fused<64><<<gblk, 512, 0, stream>>>(
        nullptr, hb + 64, rowptr, nbr,
        enc + 14336, cs_b1 + 64, enc + 18432, cs_b2 + 64,
        cs_g + 64, cs_be + 64, cs_m + 64, cs_v + 64, cs_eps + 1, hb + 128, batch, gsum, 128, N_);

    // ---- head ----
    head_kernel<<<GG, 256, 0, stream>>>(gsum, gcnt_i, nc_W1, nc_b1, nc_W2, nc_b2,
                                        nc_W3, nc_b3, nc_W4, nc_b4, class_out, comp_idx);

    // ---- edge prediction (MFMA) ----
    edge_mfma<<<(C_ + 63) / 64, 256, 0, stream>>>(
        cand, batch, comp_idx, (const short*)hb, W1b_p, W2_p, pc, ep_W3, ep_b3, scores, C_);
}

// Round 9
// 313.857 us; speedup vs baseline: 1.4205x; 1.4205x over previous
//
#include <hip/hip_runtime.h>
#include <hip/hip_bf16.h>

// Problem constants (MultiTaskFEGIN): N=100000, E=1200000, F=32, H=64, L=3,
// G=256, C=200000, NC=10, D=L*H=192.

#define GG 256
#define NCC 10
#define DD 192
#define BSH 9          // bucket shift: 512 nodes/bucket (NB <= 256 for N <= 131072)

typedef short bf16x8 __attribute__((ext_vector_type(8)));
typedef float f32x4  __attribute__((ext_vector_type(4)));

__device__ inline unsigned short f2bf_u(float x) {
    __hip_bfloat16 h = __float2bfloat16(x);
    return *reinterpret_cast<unsigned short*>(&h);
}
__device__ inline float bf2f(unsigned short u) {
    return __uint_as_float(((unsigned int)u) << 16);
}

// ---------------------------------------------------------------------------
// Binned CSR build (R6, unchanged): contiguous per-bucket scatter regions.
// ---------------------------------------------------------------------------
__global__ void bin_hist(const int* __restrict__ dst, int* __restrict__ bcnt, int E_) {
    __shared__ int h[256];
    h[threadIdx.x] = 0;
    __syncthreads();
    for (int e = blockIdx.x * 256 + threadIdx.x; e < E_; e += gridDim.x * 256)
        atomicAdd(&h[dst[e] >> BSH], 1);
    __syncthreads();
    if (h[threadIdx.x]) atomicAdd(&bcnt[threadIdx.x], h[threadIdx.x]);
}

__global__ void bin_scan(const int* __restrict__ bcnt, int* __restrict__ bbase,
                         int* __restrict__ bpos, int NB, int E_) {
    __shared__ int s[256];
    const int t = threadIdx.x;
    int v = (t < NB) ? bcnt[t] : 0;
    s[t] = v;
    __syncthreads();
    for (int off = 1; off < 256; off <<= 1) {
        int x = (t >= off) ? s[t - off] : 0;
        __syncthreads();
        s[t] += x;
        __syncthreads();
    }
    if (t < NB) { bbase[t] = s[t] - v; bpos[t] = s[t] - v; }
    if (t == 0) bbase[NB] = E_;
}

__global__ __launch_bounds__(256) void bin_scatter(
    const int* __restrict__ src, const int* __restrict__ dst,
    int* __restrict__ bpos, int2* __restrict__ ebuf, int E_) {
    __shared__ int h[256];
    __shared__ int base[256];
    const int t = threadIdx.x;
    const int e0 = blockIdx.x * 2048;
    h[t] = 0;
    __syncthreads();
    int myb[8], mys[8], myd[8], myr[8];
    #pragma unroll
    for (int u = 0; u < 8; ++u) {
        int e = e0 + t + u * 256;
        if (e < E_) {
            int d = dst[e];
            myb[u] = d >> BSH;
            myd[u] = d;
            mys[u] = src[e];
            myr[u] = atomicAdd(&h[myb[u]], 1);
        } else myb[u] = -1;
    }
    __syncthreads();
    if (h[t]) base[t] = atomicAdd(&bpos[t], h[t]);
    __syncthreads();
    #pragma unroll
    for (int u = 0; u < 8; ++u)
        if (myb[u] >= 0)
            ebuf[base[myb[u]] + myr[u]] = make_int2(mys[u], myd[u]);
}

__global__ __launch_bounds__(256) void csr_bucket(
    const int2* __restrict__ ebuf, const int* __restrict__ bbase,
    int* __restrict__ rowptr, int* __restrict__ nbr, int N_, int NB) {
    __shared__ int lh[512];
    __shared__ int lx[512];
    __shared__ int ps[256];
    const int b = blockIdx.x;
    const int t = threadIdx.x;
    const int ebase = bbase[b], eend = bbase[b + 1];
    const int ecnt = eend - ebase;
    const int n0 = b << BSH;

    for (int i = t; i < 512; i += 256) lh[i] = 0;
    __syncthreads();
    for (int i = t; i < ecnt; i += 256)
        atomicAdd(&lh[ebuf[ebase + i].y - n0], 1);
    __syncthreads();

    int pv = lh[2 * t] + lh[2 * t + 1];
    ps[t] = pv;
    __syncthreads();
    for (int off = 1; off < 256; off <<= 1) {
        int x = (t >= off) ? ps[t - off] : 0;
        __syncthreads();
        ps[t] += x;
        __syncthreads();
    }
    const int excl = ps[t] - pv;
    lx[2 * t] = excl;
    lx[2 * t + 1] = excl + lh[2 * t];
    __syncthreads();

    for (int i = t; i < 512; i += 256) {
        int n = n0 + i;
        if (n < N_) rowptr[n] = ebase + lx[i];
    }
    if (b == NB - 1 && t == 0) rowptr[N_] = eend;

    for (int i = t; i < 512; i += 256) lh[i] = lx[i];
    __syncthreads();
    for (int i = t; i < ecnt; i += 256) {
        int2 p = ebuf[ebase + i];
        int r = atomicAdd(&lh[p.y - n0], 1);
        nbr[ebase + r] = p.x;
    }
}

// ---------------------------------------------------------------------------
// prep_enc: pack the 6 encoder weight matrices into MFMA B-fragment bf16.
// ---------------------------------------------------------------------------
__global__ void prep_enc(const float* __restrict__ c1W1, const float* __restrict__ c1W2,
                         const float* __restrict__ csW1, const float* __restrict__ csW2,
                         unsigned short* __restrict__ enc) {
    int idx = blockIdx.x * 256 + threadIdx.x;
    if (idx >= 22528) return;
    const float* W; int rel;
    if (idx < 2048)       { W = c1W1;        rel = idx; }
    else if (idx < 6144)  { W = c1W2;        rel = idx - 2048; }
    else if (idx < 10240) { W = csW1;        rel = idx - 6144; }
    else if (idx < 14336) { W = csW2;        rel = idx - 10240; }
    else if (idx < 18432) { W = csW1 + 4096; rel = idx - 14336; }
    else                  { W = csW2 + 4096; rel = idx - 18432; }
    int frag = rel >> 9;
    int lane = (rel >> 3) & 63;
    int j = rel & 7;
    int ks = frag >> 2, nt = frag & 3;
    int k = ks * 32 + ((lane >> 4) << 3) + j;
    int n = nt * 16 + (lane & 15);
    enc[idx] = f2bf_u(W[k * 64 + n]);
}

// ---------------------------------------------------------------------------
// gcnt by binary search (batch sorted): gcnt[g] = lb(g+1) - lb(g).
// One block, 256 threads, zero atomics (the R8 atomic version serialized on
// same-address RMWs from sorted batch: 147us -> ~3us).
// ---------------------------------------------------------------------------
__global__ void gcnt_bs(const int* __restrict__ batch, int* __restrict__ gcnt_i, int N_) {
    __shared__ int lbs[GG + 1];
    const int g = threadIdx.x;
    int lo = 0, hi = N_;
    while (lo < hi) {
        int mid = (lo + hi) >> 1;
        if (batch[mid] < g) lo = mid + 1; else hi = mid;
    }
    lbs[g] = lo;
    if (g == 0) lbs[GG] = N_;
    __syncthreads();
    gcnt_i[g] = lbs[g + 1] - lbs[g];
}

// ---------------------------------------------------------------------------
// Fused GIN layer: combined-span chunked gather (deep ILP) -> bf16 swizzled
// LDS -> MFMA 2-layer MLP -> BN -> bf16 hb slice + fused per-slice mean-pool
// accumulation (batch sorted: per-block run-length, atomics to L2-resident
// gsum). 32 nodes/block, 512 thr. LDS ~12KB. nbr[] padded >=64 ints past E.
// ---------------------------------------------------------------------------
#define SWZ(row, byte) ((byte) ^ (((row) & 7) << 4))

template<int K>
__global__ __launch_bounds__(512) void gin_fused(
    const float* __restrict__ x32,                 // K=32: fp32 input [N][32]
    const __hip_bfloat16* __restrict__ hin_b,      // K=64: bf16 slice, stride DD
    const int* __restrict__ rowptr, const int* __restrict__ nbr,
    const unsigned short* __restrict__ W1p, const float* __restrict__ b1,
    const unsigned short* __restrict__ W2p, const float* __restrict__ b2,
    const float* __restrict__ gamma, const float* __restrict__ beta,
    const float* __restrict__ mean, const float* __restrict__ var,
    const float* __restrict__ eps_p,
    __hip_bfloat16* __restrict__ out_b,            // slice ptr, stride DD
    const int* __restrict__ batch, float* __restrict__ gsum, int soff,
    int N_) {
    __shared__ char s_agg[32 * 128];   // bf16 [32 nodes][64 k], XOR-swizzled
    __shared__ char s_h1[32 * 128];
    __shared__ char s_out[32 * 128];
    __shared__ int sb[32];

    const int t = threadIdx.x;
    const int lane = t & 63;
    const int w = t >> 6;
    const int node0 = blockIdx.x * 32;
    const int nb = w * 4;

    if (t < 32) sb[t] = (node0 + t < N_) ? batch[node0 + t] : -1;

    const float eps1 = 1.0f + eps_p[0];

    // ---- combined-span gather for this wave's 4 consecutive nodes ----
    const int n0w = node0 + nb;
    const int rp0 = __builtin_amdgcn_readfirstlane(rowptr[min(n0w + 0, N_)]);
    const int rp1 = __builtin_amdgcn_readfirstlane(rowptr[min(n0w + 1, N_)]);
    const int rp2 = __builtin_amdgcn_readfirstlane(rowptr[min(n0w + 2, N_)]);
    const int rp3 = __builtin_amdgcn_readfirstlane(rowptr[min(n0w + 3, N_)]);
    const int rp4 = __builtin_amdgcn_readfirstlane(rowptr[min(n0w + 4, N_)]);
    const int cnt = rp4 - rp0;
    const int e1 = rp1 - rp0, e2 = rp2 - rp0, e3 = rp3 - rp0;
    const int* nbp = nbr + rp0;

    float a0 = 0.f, a1 = 0.f, a2 = 0.f, a3 = 0.f;

    if (K == 64) {
        const __hip_bfloat16* hbp = hin_b + lane;
        int idxb[16];
        #pragma unroll
        for (int u = 0; u < 16; ++u) idxb[u] = nbp[u];
        for (int k = 0; k < cnt; k += 16) {
            int nxt[16];
            #pragma unroll
            for (int u = 0; u < 16; ++u) nxt[u] = nbp[k + 16 + u];
            #pragma unroll
            for (int u = 0; u < 16; ++u) {
                float v = __bfloat162float(hbp[(size_t)idxb[u] * DD]);
                int j = k + u;
                a0 += (j < e1)             ? v : 0.f;
                a1 += (j >= e1 && j < e2)  ? v : 0.f;
                a2 += (j >= e2 && j < e3)  ? v : 0.f;
                a3 += (j >= e3 && j < cnt) ? v : 0.f;
            }
            #pragma unroll
            for (int u = 0; u < 16; ++u) idxb[u] = nxt[u];
        }
        if (n0w + 0 < N_) a0 += eps1 * __bfloat162float(hbp[(size_t)(n0w + 0) * DD]);
        if (n0w + 1 < N_) a1 += eps1 * __bfloat162float(hbp[(size_t)(n0w + 1) * DD]);
        if (n0w + 2 < N_) a2 += eps1 * __bfloat162float(hbp[(size_t)(n0w + 2) * DD]);
        if (n0w + 3 < N_) a3 += eps1 * __bfloat162float(hbp[(size_t)(n0w + 3) * DD]);
        *(unsigned short*)(s_agg + SWZ(nb + 0, (nb + 0) * 128 + lane * 2)) = f2bf_u(a0);
        *(unsigned short*)(s_agg + SWZ(nb + 1, (nb + 1) * 128 + lane * 2)) = f2bf_u(a1);
        *(unsigned short*)(s_agg + SWZ(nb + 2, (nb + 2) * 128 + lane * 2)) = f2bf_u(a2);
        *(unsigned short*)(s_agg + SWZ(nb + 3, (nb + 3) * 128 + lane * 2)) = f2bf_u(a3);
    } else {
        // K == 32: fp32 rows; lanes 0-31 = even edges, 32-63 = odd edges
        const int d = lane & 31, rs = lane >> 5;
        const float* xp = x32 + d;
        int idxb[8];
        #pragma unroll
        for (int u = 0; u < 8; ++u) idxb[u] = nbp[2 * u + rs];
        for (int k = 0; k < cnt; k += 16) {
            int nxt[8];
            #pragma unroll
            for (int u = 0; u < 8; ++u) nxt[u] = nbp[k + 16 + 2 * u + rs];
            #pragma unroll
            for (int u = 0; u < 8; ++u) {
                float v = xp[(size_t)idxb[u] * 32];
                int j = k + 2 * u + rs;
                a0 += (j < e1)             ? v : 0.f;
                a1 += (j >= e1 && j < e2)  ? v : 0.f;
                a2 += (j >= e2 && j < e3)  ? v : 0.f;
                a3 += (j >= e3 && j < cnt) ? v : 0.f;
            }
            #pragma unroll
            for (int u = 0; u < 8; ++u) idxb[u] = nxt[u];
        }
        a0 += __shfl_xor(a0, 32);
        a1 += __shfl_xor(a1, 32);
        a2 += __shfl_xor(a2, 32);
        a3 += __shfl_xor(a3, 32);
        if (rs == 0) {
            if (n0w + 0 < N_) a0 += eps1 * xp[(size_t)(n0w + 0) * 32];
            if (n0w + 1 < N_) a1 += eps1 * xp[(size_t)(n0w + 1) * 32];
            if (n0w + 2 < N_) a2 += eps1 * xp[(size_t)(n0w + 2) * 32];
            if (n0w + 3 < N_) a3 += eps1 * xp[(size_t)(n0w + 3) * 32];
            *(unsigned short*)(s_agg + SWZ(nb + 0, (nb + 0) * 128 + d * 2)) = f2bf_u(a0);
            *(unsigned short*)(s_agg + SWZ(nb + 1, (nb + 1) * 128 + d * 2)) = f2bf_u(a1);
            *(unsigned short*)(s_agg + SWZ(nb + 2, (nb + 2) * 128 + d * 2)) = f2bf_u(a2);
            *(unsigned short*)(s_agg + SWZ(nb + 3, (nb + 3) * 128 + d * 2)) = f2bf_u(a3);
        }
    }
    __syncthreads();

    // ---- GEMM1: [32 x K] @ [K x 64] via MFMA; wave w -> C tile (mt, nt) ----
    const int mt = w >> 2, nt = w & 3;
    const int arow = mt * 16 + (lane & 15);
    const int col = nt * 16 + (lane & 15);
    f32x4 c1v = (f32x4){0.f, 0.f, 0.f, 0.f};
    #pragma unroll
    for (int ks = 0; ks < K / 32; ++ks) {
        bf16x8 a = *(const bf16x8*)(s_agg + SWZ(arow, arow * 128 + ks * 64 + ((lane >> 4) << 4)));
        bf16x8 b = *(const bf16x8*)(W1p + (((ks << 2) + nt) << 9) + (lane << 3));
        c1v = __builtin_amdgcn_mfma_f32_16x16x32_bf16(a, b, c1v, 0, 0, 0);
    }
    {
        const float bb1 = b1[col];
        #pragma unroll
        for (int reg = 0; reg < 4; ++reg) {
            int row = mt * 16 + ((lane >> 4) << 2) + reg;
            float v = fmaxf(c1v[reg] + bb1, 0.f);
            *(unsigned short*)(s_h1 + SWZ(row, row * 128 + col * 2)) = f2bf_u(v);
        }
    }
    __syncthreads();

    // ---- GEMM2: [32 x 64] @ [64 x 64] + BN epilogue ----
    f32x4 c2v = (f32x4){0.f, 0.f, 0.f, 0.f};
    #pragma unroll
    for (int ks = 0; ks < 2; ++ks) {
        bf16x8 a = *(const bf16x8*)(s_h1 + SWZ(arow, arow * 128 + ks * 64 + ((lane >> 4) << 4)));
        bf16x8 b = *(const bf16x8*)(W2p + (((ks << 2) + nt) << 9) + (lane << 3));
        c2v = __builtin_amdgcn_mfma_f32_16x16x32_bf16(a, b, c2v, 0, 0, 0);
    }
    {
        const float bb2 = b2[col];
        const float ga = gamma[col], bet = beta[col], mu = mean[col];
        const float iv = rsqrtf(var[col] + 1e-5f);
        #pragma unroll
        for (int reg = 0; reg < 4; ++reg) {
            int row = mt * 16 + ((lane >> 4) << 2) + reg;
            float v = fmaxf(c2v[reg] + bb2, 0.f);
            v = ga * (v - mu) * iv + bet;
            *(unsigned short*)(s_out + SWZ(row, row * 128 + col * 2)) = f2bf_u(v);
        }
    }
    __syncthreads();

    // ---- coalesced copy out: 32 rows x 128B, 16 threads/row x 8B ----
    {
        int r = t >> 4, c8 = t & 15;
        int node = node0 + r;
        if (node < N_) {
            ushort4 v = *(const ushort4*)(s_out + SWZ(r, r * 128 + c8 * 8));
            *(ushort4*)((unsigned short*)out_b + (size_t)node * DD + c8 * 4) = v;
        }
    }

    // ---- fused mean-pool accumulation for this slice (batch sorted) ----
    if (t < 256) {
        const int d = t & 63;
        const int rg = t >> 6;                  // row group 0..3 (8 rows each)
        float acc = 0.f;
        int curg = sb[rg * 8];
        #pragma unroll
        for (int r = rg * 8; r < rg * 8 + 8; ++r) {
            int g = sb[r];
            if (g != curg) {
                if (curg >= 0) atomicAdd(&gsum[curg * DD + soff + d], acc);
                acc = 0.f; curg = g;
            }
            if (g >= 0)
                acc += bf2f(*(const unsigned short*)(s_out + SWZ(r, r * 128 + d * 2)));
        }
        if (curg >= 0) atomicAdd(&gsum[curg * DD + soff + d], acc);
    }
}

// ---------------------------------------------------------------------------
// Classification head: one block per graph (fp32 throughout).
// ---------------------------------------------------------------------------
__global__ void head_kernel(const float* __restrict__ gsum, const int* __restrict__ gcnt_i,
                            const float* __restrict__ W1, const float* __restrict__ b1,
                            const float* __restrict__ W2, const float* __restrict__ b2,
                            const float* __restrict__ W3, const float* __restrict__ b3,
                            const float* __restrict__ W4, const float* __restrict__ b4,
                            float* __restrict__ class_out, int* __restrict__ comp_idx) {
    const int g = blockIdx.x;
    const int t = threadIdx.x;
    __shared__ float ge[DD], h1[128], h2[64], h3[64], logits[NCC];

    const float c = fmaxf((float)gcnt_i[g], 1.0f);
    if (t < DD) ge[t] = gsum[g * DD + t] / c;
    __syncthreads();

    if (t < 128) {
        float a = b1[t];
        #pragma unroll 4
        for (int k = 0; k < DD; ++k) a += ge[k] * W1[k * 128 + t];
        h1[t] = fmaxf(a, 0.0f);
    }
    __syncthreads();
    if (t < 64) {
        float a = b2[t];
        #pragma unroll 4
        for (int k = 0; k < 128; ++k) a += h1[k] * W2[k * 64 + t];
        h2[t] = fmaxf(a, 0.0f);
    }
    __syncthreads();
    if (t < 64) {
        float a = b3[t];
        #pragma unroll 4
        for (int k = 0; k < 64; ++k) a += h2[k] * W3[k * 64 + t];
        h3[t] = fmaxf(a, 0.0f);
    }
    __syncthreads();
    if (t < NCC) {
        float a = b4[t];
        #pragma unroll
        for (int k = 0; k < 64; ++k) a += h3[k] * W4[k * NCC + t];
        logits[t] = a;
    }
    __syncthreads();
    if (t == 0) {
        float mx = logits[0]; int am = 0;
        for (int j = 1; j < NCC; ++j) if (logits[j] > mx) { mx = logits[j]; am = j; }
        float se = 0.0f;
        for (int j = 0; j < NCC; ++j) se += expf(logits[j] - mx);
        float lse = logf(se);
        for (int j = 0; j < NCC; ++j) class_out[g * NCC + j] = logits[j] - mx - lse;
        comp_idx[g] = am;
    }
}

// ---------------------------------------------------------------------------
// prep_edge: pack ep_W1 (rows 192..383) and ep_W2 into MFMA B-fragment order;
// pc[10][128] = comp_emb @ W1a + b1.
// ---------------------------------------------------------------------------
__global__ void prep_edge(const float* __restrict__ W1, const float* __restrict__ b1,
                          const float* __restrict__ W2, const float* __restrict__ comp_emb,
                          unsigned short* __restrict__ W1b_p, unsigned short* __restrict__ W2_p,
                          float* __restrict__ pc) {
    int idx = blockIdx.x * 256 + threadIdx.x;
    const int S1 = 6 * 8 * 512;
    const int S2 = 4 * 4 * 512;
    if (idx < S1) {
        int frag = idx >> 9;
        int lane = (idx >> 3) & 63;
        int j = idx & 7;
        int kstep = frag >> 3, nt = frag & 7;
        int k = kstep * 32 + ((lane >> 4) << 3) + j;
        int n = nt * 16 + (lane & 15);
        W1b_p[idx] = f2bf_u(W1[(192 + k) * 128 + n]);
    } else if (idx < S1 + S2) {
        int i2 = idx - S1;
        int frag = i2 >> 9;
        int lane = (i2 >> 3) & 63;
        int j = i2 & 7;
        int kstep = frag >> 2, nt = frag & 3;
        int k = kstep * 32 + ((lane >> 4) << 3) + j;
        int n = nt * 16 + (lane & 15);
        W2_p[i2] = f2bf_u(W2[k * 64 + n]);
    } else if (idx < S1 + S2 + NCC * 128) {
        int i3 = idx - (S1 + S2);
        int ci = i3 >> 7, col = i3 & 127;
        float a = b1[col];
        for (int k = 0; k < DD; ++k) a += comp_emb[ci * DD + k] * W1[k * 128 + col];
        pc[i3] = a;
    }
}

// ---------------------------------------------------------------------------
// edge_mfma: 64 candidates per 256-thread block (4 waves). de rows gathered
// directly from bf16 hb (384B/row).
// ---------------------------------------------------------------------------
__global__ __launch_bounds__(256) void edge_mfma(
    const int* __restrict__ cand, const int* __restrict__ batch,
    const int* __restrict__ comp_idx, const short* __restrict__ hb,
    const unsigned short* __restrict__ W1b_p, const unsigned short* __restrict__ W2_p,
    const float* __restrict__ pc, const float* __restrict__ W3,
    const float* __restrict__ b3, float* __restrict__ scores, int C_) {
    __shared__ char s_de[64 * 384];
    __shared__ char s_h1[64 * 256];
    __shared__ int s_node[64];
    __shared__ int s_ci[64];
    __shared__ float s_pc[NCC * 128];
    __shared__ float s_w3[64];

    const int t = threadIdx.x;
    const int lane = t & 63;
    const int w = t >> 6;
    const int c0 = blockIdx.x * 64;

    if (t < 64) {
        int c = c0 + t;
        int node = (c < C_) ? cand[c] : cand[0];
        s_node[t] = node;
        s_ci[t] = comp_idx[batch[node]];
        s_w3[t] = W3[t];
    }
    for (int i = t; i < NCC * 128; i += 256) s_pc[i] = pc[i];
    __syncthreads();

    for (int i = t; i < 64 * 24; i += 256) {
        int r = i / 24, c8 = i - r * 24;
        bf16x8 v = *(const bf16x8*)(hb + (size_t)s_node[r] * DD + c8 * 8);
        int off = r * 384 + c8 * 16;
        *(bf16x8*)(s_de + (off ^ ((r & 7) << 4))) = v;
    }
    __syncthreads();

    f32x4 acc1[8];
    #pragma unroll
    for (int nt = 0; nt < 8; ++nt) acc1[nt] = (f32x4){0.f, 0.f, 0.f, 0.f};
    const int arow = w * 16 + (lane & 15);
    const int abase = arow * 384 + ((lane >> 4) << 4);
    #pragma unroll
    for (int ks = 0; ks < 6; ++ks) {
        bf16x8 a = *(const bf16x8*)(s_de + ((abase + ks * 64) ^ ((arow & 7) << 4)));
        #pragma unroll
        for (int nt = 0; nt < 8; ++nt) {
            bf16x8 b = *(const bf16x8*)(W1b_p + ((ks * 8 + nt) << 9) + (lane << 3));
            acc1[nt] = __builtin_amdgcn_mfma_f32_16x16x32_bf16(a, b, acc1[nt], 0, 0, 0);
        }
    }
    {
        const int rq = (lane >> 4) << 2;
        #pragma unroll
        for (int reg = 0; reg < 4; ++reg) {
            int row = w * 16 + rq + reg;
            int ci = s_ci[row];
            #pragma unroll
            for (int nt = 0; nt < 8; ++nt) {
                int col = nt * 16 + (lane & 15);
                float v = acc1[nt][reg] + s_pc[ci * 128 + col];
                v = fmaxf(v, 0.0f);
                int off = row * 256 + col * 2;
                *(unsigned short*)(s_h1 + (off ^ ((row & 7) << 4))) = f2bf_u(v);
            }
        }
    }
    __syncthreads();

    f32x4 acc2[4];
    #pragma unroll
    for (int nt = 0; nt < 4; ++nt) acc2[nt] = (f32x4){0.f, 0.f, 0.f, 0.f};
    const int a2base = arow * 256 + ((lane >> 4) << 4);
    #pragma unroll
    for (int ks = 0; ks < 4; ++ks) {
        bf16x8 a = *(const bf16x8*)(s_h1 + ((a2base + ks * 64) ^ ((arow & 7) << 4)));
        #pragma unroll
        for (int nt = 0; nt < 4; ++nt) {
            bf16x8 b = *(const bf16x8*)(W2_p + ((ks * 4 + nt) << 9) + (lane << 3));
            acc2[nt] = __builtin_amdgcn_mfma_f32_16x16x32_bf16(a, b, acc2[nt], 0, 0, 0);
        }
    }
    const float bb3 = b3[0];
    #pragma unroll
    for (int reg = 0; reg < 4; ++reg) {
        float p = 0.0f;
        #pragma unroll
        for (int nt = 0; nt < 4; ++nt)
            p += fmaxf(acc2[nt][reg], 0.0f) * s_w3[nt * 16 + (lane & 15)];
        p += __shfl_xor(p, 1);
        p += __shfl_xor(p, 2);
        p += __shfl_xor(p, 4);
        p += __shfl_xor(p, 8);
        if ((lane & 15) == 0) {
            int c = c0 + w * 16 + ((lane >> 4) << 2) + reg;
            if (c < C_) scores[c] = 1.0f / (1.0f + expf(-(p + bb3)));
        }
    }
}

// ---------------------------------------------------------------------------
extern "C" void kernel_launch(void* const* d_in, const int* in_sizes, int n_in,
                              void* d_out, int out_size, void* d_ws, size_t ws_size,
                              hipStream_t stream) {
    const float* x        = (const float*)d_in[0];
    const int*   ei       = (const int*)d_in[1];
    const int*   batch    = (const int*)d_in[2];
    const int*   cand     = (const int*)d_in[3];
    const float* c1_W1    = (const float*)d_in[4];
    const float* c1_b1    = (const float*)d_in[5];
    const float* c1_W2    = (const float*)d_in[6];
    const float* c1_b2    = (const float*)d_in[7];
    const float* c1_g     = (const float*)d_in[8];
    const float* c1_be    = (const float*)d_in[9];
    const float* c1_m     = (const float*)d_in[10];
    const float* c1_v     = (const float*)d_in[11];
    const float* c1_eps   = (const float*)d_in[12];
    const float* cs_W1    = (const float*)d_in[13];
    const float* cs_b1    = (const float*)d_in[14];
    const float* cs_W2    = (const float*)d_in[15];
    const float* cs_b2    = (const float*)d_in[16];
    const float* cs_g     = (const float*)d_in[17];
    const float* cs_be    = (const float*)d_in[18];
    const float* cs_m     = (const float*)d_in[19];
    const float* cs_v     = (const float*)d_in[20];
    const float* cs_eps   = (const float*)d_in[21];
    const float* nc_W1    = (const float*)d_in[22];
    const float* nc_b1    = (const float*)d_in[23];
    const float* nc_W2    = (const float*)d_in[24];
    const float* nc_b2    = (const float*)d_in[25];
    const float* nc_W3    = (const float*)d_in[26];
    const float* nc_b3    = (const float*)d_in[27];
    const float* nc_W4    = (const float*)d_in[28];
    const float* nc_b4    = (const float*)d_in[29];
    const float* comp_emb = (const float*)d_in[30];
    const float* ep_W1    = (const float*)d_in[31];
    const float* ep_b1    = (const float*)d_in[32];
    const float* ep_W2    = (const float*)d_in[33];
    const float* ep_b2    = (const float*)d_in[34];
    const float* ep_W3    = (const float*)d_in[35];
    const float* ep_b3    = (const float*)d_in[36];

    const int N_ = in_sizes[0] / 32;
    const int E_ = in_sizes[1] / 2;
    const int C_ = in_sizes[3];
    const int* src = ei;
    const int* dst = ei + E_;
    const int NB = (N_ + (1 << BSH) - 1) >> BSH;

    char* ws = (char*)d_ws;
    size_t off = 0;
    __hip_bfloat16* hb = (__hip_bfloat16*)(ws + off); off += (size_t)N_ * DD * 2;
    int*   rowptr   = (int*)(ws + off);   off += (size_t)(N_ + 2) * 4;
    int*   nbr      = (int*)(ws + off);   off += (size_t)(E_ + 64) * 4;
    int*   bcnt     = (int*)(ws + off);   off += 1024;
    int*   bbase    = (int*)(ws + off);   off += 1044;
    int*   bpos     = (int*)(ws + off);   off += 1024;
    float* gsum     = (float*)(ws + off); off += (size_t)GG * DD * 4;
    int*   gcnt_i   = (int*)(ws + off);   off += 1024;
    int*   comp_idx = (int*)(ws + off);   off += 1024;
    float* pc       = (float*)(ws + off); off += NCC * 128 * 4;
    unsigned short* W1b_p = (unsigned short*)(ws + off); off += 6 * 8 * 512 * 2;
    unsigned short* W2_p  = (unsigned short*)(ws + off); off += 4 * 4 * 512 * 2;
    unsigned short* enc   = (unsigned short*)(ws + off); off += 22528 * 2;
    // ebuf (E x int2 = 9.6MB) aliases hb: fully consumed by csr_bucket before
    // the first gin_fused writes hb (same stream, serial).
    int2*  ebuf     = (int2*)hb;

    float* class_out = (float*)d_out;
    float* scores    = class_out + GG * NCC;

    // ---- weight prep (independent of graph pipeline) ----
    prep_edge<<<(6 * 8 * 512 + 4 * 4 * 512 + NCC * 128 + 255) / 256, 256, 0, stream>>>(
        ep_W1, ep_b1, ep_W2, comp_emb, W1b_p, W2_p, pc);
    prep_enc<<<(22528 + 255) / 256, 256, 0, stream>>>(c1_W1, c1_W2, cs_W1, cs_W2, enc);

    // ---- binned CSR build ----
    hipMemsetAsync(bcnt, 0, 1024, stream);
    hipMemsetAsync(nbr + E_, 0, 64 * 4, stream);
    bin_hist<<<1024, 256, 0, stream>>>(dst, bcnt, E_);
    bin_scan<<<1, 256, 0, stream>>>(bcnt, bbase, bpos, NB, E_);
    bin_scatter<<<(E_ + 2047) / 2048, 256, 0, stream>>>(src, dst, bpos, ebuf, E_);
    csr_bucket<<<NB, 256, 0, stream>>>(ebuf, bbase, rowptr, nbr, N_, NB);

    // ---- pool accumulators ----
    hipMemsetAsync(gsum, 0, (size_t)GG * DD * 4, stream);
    gcnt_bs<<<1, GG, 0, stream>>>(batch, gcnt_i, N_);

    // ---- GIN layers (fused gather + MFMA MLP + fused pool) ----
    const int gblk = (N_ + 31) / 32;
    gin_fused<32><<<gblk, 512, 0, stream>>>(
        x, nullptr, rowptr, nbr,
        enc + 0, c1_b1, enc + 2048, c1_b2,
        c1_g, c1_be, c1_m, c1_v, c1_eps, hb + 0, batch, gsum, 0, N_);
    gin_fused<64><<<gblk, 512, 0, stream>>>(
        nullptr, hb + 0, rowptr, nbr,
        enc + 6144, cs_b1 + 0, enc + 10240, cs_b2 + 0,
        cs_g + 0, cs_be + 0, cs_m + 0, cs_v + 0, cs_eps + 0, hb + 64, batch, gsum, 64, N_);
    gin_fused<64><<<gblk, 512, 0, stream>>>(
        nullptr, hb + 64, rowptr, nbr,
        enc + 14336, cs_b1 + 64, enc + 18432, cs_b2 + 64,
        cs_g + 64, cs_be + 64, cs_m + 64, cs_v + 64, cs_eps + 1, hb + 128, batch, gsum, 128, N_);

    // ---- head ----
    head_kernel<<<GG, 256, 0, stream>>>(gsum, gcnt_i, nc_W1, nc_b1, nc_W2, nc_b2,
                                        nc_W3, nc_b3, nc_W4, nc_b4, class_out, comp_idx);

    // ---- edge prediction (MFMA) ----
    edge_mfma<<<(C_ + 63) / 64, 256, 0, stream>>>(
        cand, batch, comp_idx, (const short*)hb, W1b_p, W2_p, pc, ep_W3, ep_b3, scores, C_);
}

// Round 10
// 296.570 us; speedup vs baseline: 1.5033x; 1.0583x over previous
//
#include <hip/hip_runtime.h>
#include <hip/hip_bf16.h>

// Problem constants (MultiTaskFEGIN): N=100000, E=1200000, F=32, H=64, L=3,
// G=256, C=200000, NC=10, D=L*H=192.

#define GG 256
#define NCC 10
#define DD 192
#define BSH 9          // bucket shift: 512 nodes/bucket (NB <= 256 for N <= 131072)

typedef short bf16x8 __attribute__((ext_vector_type(8)));
typedef float f32x4  __attribute__((ext_vector_type(4)));

__device__ inline unsigned short f2bf_u(float x) {
    __hip_bfloat16 h = __float2bfloat16(x);
    return *reinterpret_cast<unsigned short*>(&h);
}
__device__ inline float bf2f(unsigned short u) {
    return __uint_as_float(((unsigned int)u) << 16);
}

// ---------------------------------------------------------------------------
// Binned CSR build (R6, unchanged): contiguous per-bucket scatter regions.
// ---------------------------------------------------------------------------
__global__ void bin_hist(const int* __restrict__ dst, int* __restrict__ bcnt, int E_) {
    __shared__ int h[256];
    h[threadIdx.x] = 0;
    __syncthreads();
    for (int e = blockIdx.x * 256 + threadIdx.x; e < E_; e += gridDim.x * 256)
        atomicAdd(&h[dst[e] >> BSH], 1);
    __syncthreads();
    if (h[threadIdx.x]) atomicAdd(&bcnt[threadIdx.x], h[threadIdx.x]);
}

__global__ void bin_scan(const int* __restrict__ bcnt, int* __restrict__ bbase,
                         int* __restrict__ bpos, int NB, int E_) {
    __shared__ int s[256];
    const int t = threadIdx.x;
    int v = (t < NB) ? bcnt[t] : 0;
    s[t] = v;
    __syncthreads();
    for (int off = 1; off < 256; off <<= 1) {
        int x = (t >= off) ? s[t - off] : 0;
        __syncthreads();
        s[t] += x;
        __syncthreads();
    }
    if (t < NB) { bbase[t] = s[t] - v; bpos[t] = s[t] - v; }
    if (t == 0) bbase[NB] = E_;
}

__global__ __launch_bounds__(256) void bin_scatter(
    const int* __restrict__ src, const int* __restrict__ dst,
    int* __restrict__ bpos, int2* __restrict__ ebuf, int E_) {
    __shared__ int h[256];
    __shared__ int base[256];
    const int t = threadIdx.x;
    const int e0 = blockIdx.x * 2048;
    h[t] = 0;
    __syncthreads();
    int myb[8], mys[8], myd[8], myr[8];
    #pragma unroll
    for (int u = 0; u < 8; ++u) {
        int e = e0 + t + u * 256;
        if (e < E_) {
            int d = dst[e];
            myb[u] = d >> BSH;
            myd[u] = d;
            mys[u] = src[e];
            myr[u] = atomicAdd(&h[myb[u]], 1);
        } else myb[u] = -1;
    }
    __syncthreads();
    if (h[t]) base[t] = atomicAdd(&bpos[t], h[t]);
    __syncthreads();
    #pragma unroll
    for (int u = 0; u < 8; ++u)
        if (myb[u] >= 0)
            ebuf[base[myb[u]] + myr[u]] = make_int2(mys[u], myd[u]);
}

__global__ __launch_bounds__(256) void csr_bucket(
    const int2* __restrict__ ebuf, const int* __restrict__ bbase,
    int* __restrict__ rowptr, int* __restrict__ nbr, int N_, int NB) {
    __shared__ int lh[512];
    __shared__ int lx[512];
    __shared__ int ps[256];
    const int b = blockIdx.x;
    const int t = threadIdx.x;
    const int ebase = bbase[b], eend = bbase[b + 1];
    const int ecnt = eend - ebase;
    const int n0 = b << BSH;

    for (int i = t; i < 512; i += 256) lh[i] = 0;
    __syncthreads();
    for (int i = t; i < ecnt; i += 256)
        atomicAdd(&lh[ebuf[ebase + i].y - n0], 1);
    __syncthreads();

    int pv = lh[2 * t] + lh[2 * t + 1];
    ps[t] = pv;
    __syncthreads();
    for (int off = 1; off < 256; off <<= 1) {
        int x = (t >= off) ? ps[t - off] : 0;
        __syncthreads();
        ps[t] += x;
        __syncthreads();
    }
    const int excl = ps[t] - pv;
    lx[2 * t] = excl;
    lx[2 * t + 1] = excl + lh[2 * t];
    __syncthreads();

    for (int i = t; i < 512; i += 256) {
        int n = n0 + i;
        if (n < N_) rowptr[n] = ebase + lx[i];
    }
    if (b == NB - 1 && t == 0) rowptr[N_] = eend;

    for (int i = t; i < 512; i += 256) lh[i] = lx[i];
    __syncthreads();
    for (int i = t; i < ecnt; i += 256) {
        int2 p = ebuf[ebase + i];
        int r = atomicAdd(&lh[p.y - n0], 1);
        nbr[ebase + r] = p.x;
    }
}

// ---------------------------------------------------------------------------
// prep_enc: pack the 6 encoder weight matrices into MFMA B-fragment bf16.
// ---------------------------------------------------------------------------
__global__ void prep_enc(const float* __restrict__ c1W1, const float* __restrict__ c1W2,
                         const float* __restrict__ csW1, const float* __restrict__ csW2,
                         unsigned short* __restrict__ enc) {
    int idx = blockIdx.x * 256 + threadIdx.x;
    if (idx >= 22528) return;
    const float* W; int rel;
    if (idx < 2048)       { W = c1W1;        rel = idx; }
    else if (idx < 6144)  { W = c1W2;        rel = idx - 2048; }
    else if (idx < 10240) { W = csW1;        rel = idx - 6144; }
    else if (idx < 14336) { W = csW2;        rel = idx - 10240; }
    else if (idx < 18432) { W = csW1 + 4096; rel = idx - 14336; }
    else                  { W = csW2 + 4096; rel = idx - 18432; }
    int frag = rel >> 9;
    int lane = (rel >> 3) & 63;
    int j = rel & 7;
    int ks = frag >> 2, nt = frag & 3;
    int k = ks * 32 + ((lane >> 4) << 3) + j;
    int n = nt * 16 + (lane & 15);
    enc[idx] = f2bf_u(W[k * 64 + n]);
}

// ---------------------------------------------------------------------------
// gcnt by binary search (batch sorted): gcnt[g] = lb(g+1) - lb(g).
// ---------------------------------------------------------------------------
__global__ void gcnt_bs(const int* __restrict__ batch, int* __restrict__ gcnt_i, int N_) {
    __shared__ int lbs[GG + 1];
    const int g = threadIdx.x;
    int lo = 0, hi = N_;
    while (lo < hi) {
        int mid = (lo + hi) >> 1;
        if (batch[mid] < g) lo = mid + 1; else hi = mid;
    }
    lbs[g] = lo;
    if (g == 0) lbs[GG] = N_;
    __syncthreads();
    gcnt_i[g] = lbs[g + 1] - lbs[g];
}

// ---------------------------------------------------------------------------
// Fused GIN layer (R7-9, unchanged): gather -> MFMA MLP -> BN -> hb + pool.
// ---------------------------------------------------------------------------
#define SWZ(row, byte) ((byte) ^ (((row) & 7) << 4))

template<int K>
__global__ __launch_bounds__(512) void gin_fused(
    const float* __restrict__ x32,                 // K=32: fp32 input [N][32]
    const __hip_bfloat16* __restrict__ hin_b,      // K=64: bf16 slice, stride DD
    const int* __restrict__ rowptr, const int* __restrict__ nbr,
    const unsigned short* __restrict__ W1p, const float* __restrict__ b1,
    const unsigned short* __restrict__ W2p, const float* __restrict__ b2,
    const float* __restrict__ gamma, const float* __restrict__ beta,
    const float* __restrict__ mean, const float* __restrict__ var,
    const float* __restrict__ eps_p,
    __hip_bfloat16* __restrict__ out_b,            // slice ptr, stride DD
    const int* __restrict__ batch, float* __restrict__ gsum, int soff,
    int N_) {
    __shared__ char s_agg[32 * 128];   // bf16 [32 nodes][64 k], XOR-swizzled
    __shared__ char s_h1[32 * 128];
    __shared__ char s_out[32 * 128];
    __shared__ int sb[32];

    const int t = threadIdx.x;
    const int lane = t & 63;
    const int w = t >> 6;
    const int node0 = blockIdx.x * 32;
    const int nb = w * 4;

    if (t < 32) sb[t] = (node0 + t < N_) ? batch[node0 + t] : -1;

    const float eps1 = 1.0f + eps_p[0];

    // ---- combined-span gather for this wave's 4 consecutive nodes ----
    const int n0w = node0 + nb;
    const int rp0 = __builtin_amdgcn_readfirstlane(rowptr[min(n0w + 0, N_)]);
    const int rp1 = __builtin_amdgcn_readfirstlane(rowptr[min(n0w + 1, N_)]);
    const int rp2 = __builtin_amdgcn_readfirstlane(rowptr[min(n0w + 2, N_)]);
    const int rp3 = __builtin_amdgcn_readfirstlane(rowptr[min(n0w + 3, N_)]);
    const int rp4 = __builtin_amdgcn_readfirstlane(rowptr[min(n0w + 4, N_)]);
    const int cnt = rp4 - rp0;
    const int e1 = rp1 - rp0, e2 = rp2 - rp0, e3 = rp3 - rp0;
    const int* nbp = nbr + rp0;

    float a0 = 0.f, a1 = 0.f, a2 = 0.f, a3 = 0.f;

    if (K == 64) {
        const __hip_bfloat16* hbp = hin_b + lane;
        int idxb[16];
        #pragma unroll
        for (int u = 0; u < 16; ++u) idxb[u] = nbp[u];
        for (int k = 0; k < cnt; k += 16) {
            int nxt[16];
            #pragma unroll
            for (int u = 0; u < 16; ++u) nxt[u] = nbp[k + 16 + u];
            #pragma unroll
            for (int u = 0; u < 16; ++u) {
                float v = __bfloat162float(hbp[(size_t)idxb[u] * DD]);
                int j = k + u;
                a0 += (j < e1)             ? v : 0.f;
                a1 += (j >= e1 && j < e2)  ? v : 0.f;
                a2 += (j >= e2 && j < e3)  ? v : 0.f;
                a3 += (j >= e3 && j < cnt) ? v : 0.f;
            }
            #pragma unroll
            for (int u = 0; u < 16; ++u) idxb[u] = nxt[u];
        }
        if (n0w + 0 < N_) a0 += eps1 * __bfloat162float(hbp[(size_t)(n0w + 0) * DD]);
        if (n0w + 1 < N_) a1 += eps1 * __bfloat162float(hbp[(size_t)(n0w + 1) * DD]);
        if (n0w + 2 < N_) a2 += eps1 * __bfloat162float(hbp[(size_t)(n0w + 2) * DD]);
        if (n0w + 3 < N_) a3 += eps1 * __bfloat162float(hbp[(size_t)(n0w + 3) * DD]);
        *(unsigned short*)(s_agg + SWZ(nb + 0, (nb + 0) * 128 + lane * 2)) = f2bf_u(a0);
        *(unsigned short*)(s_agg + SWZ(nb + 1, (nb + 1) * 128 + lane * 2)) = f2bf_u(a1);
        *(unsigned short*)(s_agg + SWZ(nb + 2, (nb + 2) * 128 + lane * 2)) = f2bf_u(a2);
        *(unsigned short*)(s_agg + SWZ(nb + 3, (nb + 3) * 128 + lane * 2)) = f2bf_u(a3);
    } else {
        // K == 32: fp32 rows; lanes 0-31 = even edges, 32-63 = odd edges
        const int d = lane & 31, rs = lane >> 5;
        const float* xp = x32 + d;
        int idxb[8];
        #pragma unroll
        for (int u = 0; u < 8; ++u) idxb[u] = nbp[2 * u + rs];
        for (int k = 0; k < cnt; k += 16) {
            int nxt[8];
            #pragma unroll
            for (int u = 0; u < 8; ++u) nxt[u] = nbp[k + 16 + 2 * u + rs];
            #pragma unroll
            for (int u = 0; u < 8; ++u) {
                float v = xp[(size_t)idxb[u] * 32];
                int j = k + 2 * u + rs;
                a0 += (j < e1)             ? v : 0.f;
                a1 += (j >= e1 && j < e2)  ? v : 0.f;
                a2 += (j >= e2 && j < e3)  ? v : 0.f;
                a3 += (j >= e3 && j < cnt) ? v : 0.f;
            }
            #pragma unroll
            for (int u = 0; u < 8; ++u) idxb[u] = nxt[u];
        }
        a0 += __shfl_xor(a0, 32);
        a1 += __shfl_xor(a1, 32);
        a2 += __shfl_xor(a2, 32);
        a3 += __shfl_xor(a3, 32);
        if (rs == 0) {
            if (n0w + 0 < N_) a0 += eps1 * xp[(size_t)(n0w + 0) * 32];
            if (n0w + 1 < N_) a1 += eps1 * xp[(size_t)(n0w + 1) * 32];
            if (n0w + 2 < N_) a2 += eps1 * xp[(size_t)(n0w + 2) * 32];
            if (n0w + 3 < N_) a3 += eps1 * xp[(size_t)(n0w + 3) * 32];
            *(unsigned short*)(s_agg + SWZ(nb + 0, (nb + 0) * 128 + d * 2)) = f2bf_u(a0);
            *(unsigned short*)(s_agg + SWZ(nb + 1, (nb + 1) * 128 + d * 2)) = f2bf_u(a1);
            *(unsigned short*)(s_agg + SWZ(nb + 2, (nb + 2) * 128 + d * 2)) = f2bf_u(a2);
            *(unsigned short*)(s_agg + SWZ(nb + 3, (nb + 3) * 128 + d * 2)) = f2bf_u(a3);
        }
    }
    __syncthreads();

    // ---- GEMM1: [32 x K] @ [K x 64] via MFMA; wave w -> C tile (mt, nt) ----
    const int mt = w >> 2, nt = w & 3;
    const int arow = mt * 16 + (lane & 15);
    const int col = nt * 16 + (lane & 15);
    f32x4 c1v = (f32x4){0.f, 0.f, 0.f, 0.f};
    #pragma unroll
    for (int ks = 0; ks < K / 32; ++ks) {
        bf16x8 a = *(const bf16x8*)(s_agg + SWZ(arow, arow * 128 + ks * 64 + ((lane >> 4) << 4)));
        bf16x8 b = *(const bf16x8*)(W1p + (((ks << 2) + nt) << 9) + (lane << 3));
        c1v = __builtin_amdgcn_mfma_f32_16x16x32_bf16(a, b, c1v, 0, 0, 0);
    }
    {
        const float bb1 = b1[col];
        #pragma unroll
        for (int reg = 0; reg < 4; ++reg) {
            int row = mt * 16 + ((lane >> 4) << 2) + reg;
            float v = fmaxf(c1v[reg] + bb1, 0.f);
            *(unsigned short*)(s_h1 + SWZ(row, row * 128 + col * 2)) = f2bf_u(v);
        }
    }
    __syncthreads();

    // ---- GEMM2: [32 x 64] @ [64 x 64] + BN epilogue ----
    f32x4 c2v = (f32x4){0.f, 0.f, 0.f, 0.f};
    #pragma unroll
    for (int ks = 0; ks < 2; ++ks) {
        bf16x8 a = *(const bf16x8*)(s_h1 + SWZ(arow, arow * 128 + ks * 64 + ((lane >> 4) << 4)));
        bf16x8 b = *(const bf16x8*)(W2p + (((ks << 2) + nt) << 9) + (lane << 3));
        c2v = __builtin_amdgcn_mfma_f32_16x16x32_bf16(a, b, c2v, 0, 0, 0);
    }
    {
        const float bb2 = b2[col];
        const float ga = gamma[col], bet = beta[col], mu = mean[col];
        const float iv = rsqrtf(var[col] + 1e-5f);
        #pragma unroll
        for (int reg = 0; reg < 4; ++reg) {
            int row = mt * 16 + ((lane >> 4) << 2) + reg;
            float v = fmaxf(c2v[reg] + bb2, 0.f);
            v = ga * (v - mu) * iv + bet;
            *(unsigned short*)(s_out + SWZ(row, row * 128 + col * 2)) = f2bf_u(v);
        }
    }
    __syncthreads();

    // ---- coalesced copy out: 32 rows x 128B, 16 threads/row x 8B ----
    {
        int r = t >> 4, c8 = t & 15;
        int node = node0 + r;
        if (node < N_) {
            ushort4 v = *(const ushort4*)(s_out + SWZ(r, r * 128 + c8 * 8));
            *(ushort4*)((unsigned short*)out_b + (size_t)node * DD + c8 * 4) = v;
        }
    }

    // ---- fused mean-pool accumulation for this slice (batch sorted) ----
    if (t < 256) {
        const int d = t & 63;
        const int rg = t >> 6;                  // row group 0..3 (8 rows each)
        float acc = 0.f;
        int curg = sb[rg * 8];
        #pragma unroll
        for (int r = rg * 8; r < rg * 8 + 8; ++r) {
            int g = sb[r];
            if (g != curg) {
                if (curg >= 0) atomicAdd(&gsum[curg * DD + soff + d], acc);
                acc = 0.f; curg = g;
            }
            if (g >= 0)
                acc += bf2f(*(const unsigned short*)(s_out + SWZ(r, r * 128 + d * 2)));
        }
        if (curg >= 0) atomicAdd(&gsum[curg * DD + soff + d], acc);
    }
}

// ---------------------------------------------------------------------------
// Classification head: one block per graph (fp32 throughout).
// ---------------------------------------------------------------------------
__global__ void head_kernel(const float* __restrict__ gsum, const int* __restrict__ gcnt_i,
                            const float* __restrict__ W1, const float* __restrict__ b1,
                            const float* __restrict__ W2, const float* __restrict__ b2,
                            const float* __restrict__ W3, const float* __restrict__ b3,
                            const float* __restrict__ W4, const float* __restrict__ b4,
                            float* __restrict__ class_out, int* __restrict__ comp_idx) {
    const int g = blockIdx.x;
    const int t = threadIdx.x;
    __shared__ float ge[DD], h1[128], h2[64], h3[64], logits[NCC];

    const float c = fmaxf((float)gcnt_i[g], 1.0f);
    if (t < DD) ge[t] = gsum[g * DD + t] / c;
    __syncthreads();

    if (t < 128) {
        float a = b1[t];
        #pragma unroll 4
        for (int k = 0; k < DD; ++k) a += ge[k] * W1[k * 128 + t];
        h1[t] = fmaxf(a, 0.0f);
    }
    __syncthreads();
    if (t < 64) {
        float a = b2[t];
        #pragma unroll 4
        for (int k = 0; k < 128; ++k) a += h1[k] * W2[k * 64 + t];
        h2[t] = fmaxf(a, 0.0f);
    }
    __syncthreads();
    if (t < 64) {
        float a = b3[t];
        #pragma unroll 4
        for (int k = 0; k < 64; ++k) a += h2[k] * W3[k * 64 + t];
        h3[t] = fmaxf(a, 0.0f);
    }
    __syncthreads();
    if (t < NCC) {
        float a = b4[t];
        #pragma unroll
        for (int k = 0; k < 64; ++k) a += h3[k] * W4[k * NCC + t];
        logits[t] = a;
    }
    __syncthreads();
    if (t == 0) {
        float mx = logits[0]; int am = 0;
        for (int j = 1; j < NCC; ++j) if (logits[j] > mx) { mx = logits[j]; am = j; }
        float se = 0.0f;
        for (int j = 0; j < NCC; ++j) se += expf(logits[j] - mx);
        float lse = logf(se);
        for (int j = 0; j < NCC; ++j) class_out[g * NCC + j] = logits[j] - mx - lse;
        comp_idx[g] = am;
    }
}

// ---------------------------------------------------------------------------
// prep_edge: pack ep_W1 (rows 192..383) and ep_W2 into MFMA B-fragment order;
// pc[10][128] = comp_emb @ W1a + b1.
// ---------------------------------------------------------------------------
__global__ void prep_edge(const float* __restrict__ W1, const float* __restrict__ b1,
                          const float* __restrict__ W2, const float* __restrict__ comp_emb,
                          unsigned short* __restrict__ W1b_p, unsigned short* __restrict__ W2_p,
                          float* __restrict__ pc) {
    int idx = blockIdx.x * 256 + threadIdx.x;
    const int S1 = 6 * 8 * 512;
    const int S2 = 4 * 4 * 512;
    if (idx < S1) {
        int frag = idx >> 9;
        int lane = (idx >> 3) & 63;
        int j = idx & 7;
        int kstep = frag >> 3, nt = frag & 7;
        int k = kstep * 32 + ((lane >> 4) << 3) + j;
        int n = nt * 16 + (lane & 15);
        W1b_p[idx] = f2bf_u(W1[(192 + k) * 128 + n]);
    } else if (idx < S1 + S2) {
        int i2 = idx - S1;
        int frag = i2 >> 9;
        int lane = (i2 >> 3) & 63;
        int j = i2 & 7;
        int kstep = frag >> 2, nt = frag & 3;
        int k = kstep * 32 + ((lane >> 4) << 3) + j;
        int n = nt * 16 + (lane & 15);
        W2_p[i2] = f2bf_u(W2[k * 64 + n]);
    } else if (idx < S1 + S2 + NCC * 128) {
        int i3 = idx - (S1 + S2);
        int ci = i3 >> 7, col = i3 & 127;
        float a = b1[col];
        for (int k = 0; k < DD; ++k) a += comp_emb[ci * DD + k] * W1[k * 128 + col];
        pc[i3] = a;
    }
}

// ---------------------------------------------------------------------------
// edge_mfma (R10): 64 candidates / 256-thread block, COL-SPLIT waves.
// Wave w owns ntiles {2w,2w+1} of GEMM1 and ntile w of GEMM2 -> each B
// fragment loaded once per block (was 4x). h1 aliases the de buffer
// (barrier-separated) and pc is read from global (L1-hot): LDS 47KB -> 26KB
// -> 5-6 blocks/CU so gather of one block overlaps MFMA of others.
// ---------------------------------------------------------------------------
__global__ __launch_bounds__(256, 5) void edge_mfma(
    const int* __restrict__ cand, const int* __restrict__ batch,
    const int* __restrict__ comp_idx, const short* __restrict__ hb,
    const unsigned short* __restrict__ W1b_p, const unsigned short* __restrict__ W2_p,
    const float* __restrict__ pc, const float* __restrict__ W3,
    const float* __restrict__ b3, float* __restrict__ scores, int C_) {
    __shared__ char s_buf[64 * 384];   // de (24KB); h1 reuses first 16KB
    __shared__ float s_part[4][64];
    __shared__ int s_node[64];
    __shared__ int s_ci[64];
    __shared__ float s_w3[64];

    const int t = threadIdx.x;
    const int lane = t & 63;
    const int w = t >> 6;
    const int c0 = blockIdx.x * 64;

    if (t < 64) {
        int c = c0 + t;
        int node = (c < C_) ? cand[c] : cand[0];
        s_node[t] = node;
        s_ci[t] = comp_idx[batch[node]];
        s_w3[t] = W3[t];
    }
    __syncthreads();

    // ---- gather de rows (bf16) -> swizzled LDS; 24 x 16B chunks per row ----
    for (int i = t; i < 64 * 24; i += 256) {
        int r = i / 24, c8 = i - r * 24;
        bf16x8 v = *(const bf16x8*)(hb + (size_t)s_node[r] * DD + c8 * 8);
        *(bf16x8*)(s_buf + SWZ(r, r * 384 + c8 * 16)) = v;
    }
    __syncthreads();

    // ---- GEMM1 (col-split): wave w -> ntiles {2w, 2w+1}, all 4 row tiles ----
    f32x4 acc1[4][2];
    #pragma unroll
    for (int rt = 0; rt < 4; ++rt)
        #pragma unroll
        for (int b = 0; b < 2; ++b) acc1[rt][b] = (f32x4){0.f, 0.f, 0.f, 0.f};
    #pragma unroll
    for (int ks = 0; ks < 6; ++ks) {
        bf16x8 b0 = *(const bf16x8*)(W1b_p + ((ks * 8 + 2 * w + 0) << 9) + (lane << 3));
        bf16x8 b1f = *(const bf16x8*)(W1b_p + ((ks * 8 + 2 * w + 1) << 9) + (lane << 3));
        #pragma unroll
        for (int rt = 0; rt < 4; ++rt) {
            int arow = rt * 16 + (lane & 15);
            bf16x8 a = *(const bf16x8*)(s_buf + SWZ(arow, arow * 384 + ks * 64 + ((lane >> 4) << 4)));
            acc1[rt][0] = __builtin_amdgcn_mfma_f32_16x16x32_bf16(a, b0, acc1[rt][0], 0, 0, 0);
            acc1[rt][1] = __builtin_amdgcn_mfma_f32_16x16x32_bf16(a, b1f, acc1[rt][1], 0, 0, 0);
        }
    }
    __syncthreads();   // all de reads done -> safe to overwrite with h1

    // ---- epilogue 1: + pc[ci], relu -> h1 (bf16, swizzled, stride 256B) ----
    #pragma unroll
    for (int rt = 0; rt < 4; ++rt) {
        #pragma unroll
        for (int reg = 0; reg < 4; ++reg) {
            int row = rt * 16 + ((lane >> 4) << 2) + reg;
            int ci = s_ci[row];
            #pragma unroll
            for (int b = 0; b < 2; ++b) {
                int col = (2 * w + b) * 16 + (lane & 15);
                float v = fmaxf(acc1[rt][b][reg] + pc[ci * 128 + col], 0.f);
                *(unsigned short*)(s_buf + SWZ(row, row * 256 + col * 2)) = f2bf_u(v);
            }
        }
    }
    __syncthreads();

    // ---- GEMM2 (col-split): wave w -> ntile w, all 4 row tiles ----
    f32x4 acc2[4];
    #pragma unroll
    for (int rt = 0; rt < 4; ++rt) acc2[rt] = (f32x4){0.f, 0.f, 0.f, 0.f};
    #pragma unroll
    for (int ks = 0; ks < 4; ++ks) {
        bf16x8 b = *(const bf16x8*)(W2_p + ((ks * 4 + w) << 9) + (lane << 3));
        #pragma unroll
        for (int rt = 0; rt < 4; ++rt) {
            int arow = rt * 16 + (lane & 15);
            bf16x8 a = *(const bf16x8*)(s_buf + SWZ(arow, arow * 256 + ks * 64 + ((lane >> 4) << 4)));
            acc2[rt] = __builtin_amdgcn_mfma_f32_16x16x32_bf16(a, b, acc2[rt], 0, 0, 0);
        }
    }

    // ---- epilogue 2: per-wave partial dot with W3 over its 16 cols ----
    {
        const float w3v = s_w3[w * 16 + (lane & 15)];
        #pragma unroll
        for (int rt = 0; rt < 4; ++rt) {
            #pragma unroll
            for (int reg = 0; reg < 4; ++reg) {
                float p = fmaxf(acc2[rt][reg], 0.f) * w3v;
                p += __shfl_xor(p, 1);
                p += __shfl_xor(p, 2);
                p += __shfl_xor(p, 4);
                p += __shfl_xor(p, 8);
                if ((lane & 15) == 0)
                    s_part[w][rt * 16 + ((lane >> 4) << 2) + reg] = p;
            }
        }
    }
    __syncthreads();

    if (t < 64) {
        int c = c0 + t;
        if (c < C_) {
            float p = s_part[0][t] + s_part[1][t] + s_part[2][t] + s_part[3][t] + b3[0];
            scores[c] = 1.0f / (1.0f + expf(-p));
        }
    }
}

// ---------------------------------------------------------------------------
extern "C" void kernel_launch(void* const* d_in, const int* in_sizes, int n_in,
                              void* d_out, int out_size, void* d_ws, size_t ws_size,
                              hipStream_t stream) {
    const float* x        = (const float*)d_in[0];
    const int*   ei       = (const int*)d_in[1];
    const int*   batch    = (const int*)d_in[2];
    const int*   cand     = (const int*)d_in[3];
    const float* c1_W1    = (const float*)d_in[4];
    const float* c1_b1    = (const float*)d_in[5];
    const float* c1_W2    = (const float*)d_in[6];
    const float* c1_b2    = (const float*)d_in[7];
    const float* c1_g     = (const float*)d_in[8];
    const float* c1_be    = (const float*)d_in[9];
    const float* c1_m     = (const float*)d_in[10];
    const float* c1_v     = (const float*)d_in[11];
    const float* c1_eps   = (const float*)d_in[12];
    const float* cs_W1    = (const float*)d_in[13];
    const float* cs_b1    = (const float*)d_in[14];
    const float* cs_W2    = (const float*)d_in[15];
    const float* cs_b2    = (const float*)d_in[16];
    const float* cs_g     = (const float*)d_in[17];
    const float* cs_be    = (const float*)d_in[18];
    const float* cs_m     = (const float*)d_in[19];
    const float* cs_v     = (const float*)d_in[20];
    const float* cs_eps   = (const float*)d_in[21];
    const float* nc_W1    = (const float*)d_in[22];
    const float* nc_b1    = (const float*)d_in[23];
    const float* nc_W2    = (const float*)d_in[24];
    const float* nc_b2    = (const float*)d_in[25];
    const float* nc_W3    = (const float*)d_in[26];
    const float* nc_b3    = (const float*)d_in[27];
    const float* nc_W4    = (const float*)d_in[28];
    const float* nc_b4    = (const float*)d_in[29];
    const float* comp_emb = (const float*)d_in[30];
    const float* ep_W1    = (const float*)d_in[31];
    const float* ep_b1    = (const float*)d_in[32];
    const float* ep_W2    = (const float*)d_in[33];
    const float* ep_b2    = (const float*)d_in[34];
    const float* ep_W3    = (const float*)d_in[35];
    const float* ep_b3    = (const float*)d_in[36];

    const int N_ = in_sizes[0] / 32;
    const int E_ = in_sizes[1] / 2;
    const int C_ = in_sizes[3];
    const int* src = ei;
    const int* dst = ei + E_;
    const int NB = (N_ + (1 << BSH) - 1) >> BSH;

    char* ws = (char*)d_ws;
    size_t off = 0;
    __hip_bfloat16* hb = (__hip_bfloat16*)(ws + off); off += (size_t)N_ * DD * 2;
    int*   rowptr   = (int*)(ws + off);   off += (size_t)(N_ + 2) * 4;
    int*   nbr      = (int*)(ws + off);   off += (size_t)(E_ + 64) * 4;
    int*   bcnt     = (int*)(ws + off);   off += 1024;
    int*   bbase    = (int*)(ws + off);   off += 1044;
    int*   bpos     = (int*)(ws + off);   off += 1024;
    float* gsum     = (float*)(ws + off); off += (size_t)GG * DD * 4;
    int*   gcnt_i   = (int*)(ws + off);   off += 1024;
    int*   comp_idx = (int*)(ws + off);   off += 1024;
    float* pc       = (float*)(ws + off); off += NCC * 128 * 4;
    unsigned short* W1b_p = (unsigned short*)(ws + off); off += 6 * 8 * 512 * 2;
    unsigned short* W2_p  = (unsigned short*)(ws + off); off += 4 * 4 * 512 * 2;
    unsigned short* enc   = (unsigned short*)(ws + off); off += 22528 * 2;
    // ebuf (E x int2 = 9.6MB) aliases hb: fully consumed by csr_bucket before
    // the first gin_fused writes hb (same stream, serial).
    int2*  ebuf     = (int2*)hb;

    float* class_out = (float*)d_out;
    float* scores    = class_out + GG * NCC;

    // ---- weight prep (independent of graph pipeline) ----
    prep_edge<<<(6 * 8 * 512 + 4 * 4 * 512 + NCC * 128 + 255) / 256, 256, 0, stream>>>(
        ep_W1, ep_b1, ep_W2, comp_emb, W1b_p, W2_p, pc);
    prep_enc<<<(22528 + 255) / 256, 256, 0, stream>>>(c1_W1, c1_W2, cs_W1, cs_W2, enc);

    // ---- binned CSR build ----
    hipMemsetAsync(bcnt, 0, 1024, stream);
    hipMemsetAsync(nbr + E_, 0, 64 * 4, stream);
    bin_hist<<<1024, 256, 0, stream>>>(dst, bcnt, E_);
    bin_scan<<<1, 256, 0, stream>>>(bcnt, bbase, bpos, NB, E_);
    bin_scatter<<<(E_ + 2047) / 2048, 256, 0, stream>>>(src, dst, bpos, ebuf, E_);
    csr_bucket<<<NB, 256, 0, stream>>>(ebuf, bbase, rowptr, nbr, N_, NB);

    // ---- pool accumulators ----
    hipMemsetAsync(gsum, 0, (size_t)GG * DD * 4, stream);
    gcnt_bs<<<1, GG, 0, stream>>>(batch, gcnt_i, N_);

    // ---- GIN layers (fused gather + MFMA MLP + fused pool) ----
    const int gblk = (N_ + 31) / 32;
    gin_fused<32><<<gblk, 512, 0, stream>>>(
        x, nullptr, rowptr, nbr,
        enc + 0, c1_b1, enc + 2048, c1_b2,
        c1_g, c1_be, c1_m, c1_v, c1_eps, hb + 0, batch, gsum, 0, N_);
    gin_fused<64><<<gblk, 512, 0, stream>>>(
        nullptr, hb + 0, rowptr, nbr,
        enc + 6144, cs_b1 + 0, enc + 10240, cs_b2 + 0,
        cs_g + 0, cs_be + 0, cs_m + 0, cs_v + 0, cs_eps + 0, hb + 64, batch, gsum, 64, N_);
    gin_fused<64><<<gblk, 512, 0, stream>>>(
        nullptr, hb + 64, rowptr, nbr,
        enc + 14336, cs_b1 + 64, enc + 18432, cs_b2 + 64,
        cs_g + 64, cs_be + 64, cs_m + 64, cs_v + 64, cs_eps + 1, hb + 128, batch, gsum, 128, N_);

    // ---- head ----
    head_kernel<<<GG, 256, 0, stream>>>(gsum, gcnt_i, nc_W1, nc_b1, nc_W2, nc_b2,
                                        nc_W3, nc_b3, nc_W4, nc_b4, class_out, comp_idx);

    // ---- edge prediction (MFMA) ----
    edge_mfma<<<(C_ + 63) / 64, 256, 0, stream>>>(
        cand, batch, comp_idx, (const short*)hb, W1b_p, W2_p, pc, ep_W3, ep_b3, scores, C_);
}